// Round 1
// baseline (273.972 us; speedup 1.0000x reference)
//
#include <hip/hip_runtime.h>

#define DIM   1024
#define DST   16
#define NSEQ  8192
#define NB    4

// ---------------------------------------------------------------------------
// Kernel 1: T[b][s][n] = sum_c x[b][n][c] * A[c][s]   (state stored transposed)
// Block = 256 threads, tile = 64 rows (n) x full S=16, K staged in chunks of 128.
// Thread t: s = t&15, mg = t>>4 -> owns rows mg*4..mg*4+3 for one s.
// LDS padded to 132 floats/row: 2-way bank aliasing max (free), 16B-aligned.
// ---------------------------------------------------------------------------
#define K1_MT   64
#define K1_KC   128
#define K1_KCP  132

__global__ __launch_bounds__(256) void k1_gemm(const float* __restrict__ x,
                                               const float* __restrict__ A,
                                               float* __restrict__ T) {
    __shared__ float xs[K1_MT * K1_KCP];   // 33,792 B
    __shared__ float at[DST * K1_KCP];     //  8,448 B
    const int t  = threadIdx.x;
    const int b  = blockIdx.x >> 7;            // 128 tiles per batch
    const int n0 = (blockIdx.x & 127) * K1_MT;
    const int s  = t & 15;
    const int mg = t >> 4;                     // 0..15

    const float* xrow = x + ((long)(b * NSEQ + n0)) * DIM;

    float acc0 = 0.f, acc1 = 0.f, acc2 = 0.f, acc3 = 0.f;

    for (int kc = 0; kc < DIM; kc += K1_KC) {
        // --- stage x tile: 64 rows x 128 cols (coalesced float4) ---
        {
            const int q  = t & 31;    // column quad within chunk
            const int r0 = t >> 5;    // 0..7
            #pragma unroll
            for (int it = 0; it < 8; ++it) {
                const int m = it * 8 + r0;
                const float4 v = *(const float4*)(xrow + (long)m * DIM + kc + 4 * q);
                *(float4*)&xs[m * K1_KCP + 4 * q] = v;
            }
        }
        // --- stage A^T chunk: at[s][k] (coalesced reads of A[k][s]) ---
        {
            #pragma unroll
            for (int it = 0; it < 8; ++it) {
                const int idx = it * 256 + t;
                const int kl  = idx >> 4;   // 0..127
                const int ss  = idx & 15;
                at[ss * K1_KCP + kl] = A[(kc + kl) * DST + ss];
            }
        }
        __syncthreads();

        #pragma unroll 4
        for (int kq = 0; kq < K1_KC / 4; ++kq) {
            const float4 a  = *(const float4*)&at[s * K1_KCP + 4 * kq];
            const float4 x0 = *(const float4*)&xs[(mg * 4 + 0) * K1_KCP + 4 * kq];
            const float4 x1 = *(const float4*)&xs[(mg * 4 + 1) * K1_KCP + 4 * kq];
            const float4 x2 = *(const float4*)&xs[(mg * 4 + 2) * K1_KCP + 4 * kq];
            const float4 x3 = *(const float4*)&xs[(mg * 4 + 3) * K1_KCP + 4 * kq];
            acc0 += x0.x * a.x + x0.y * a.y + x0.z * a.z + x0.w * a.w;
            acc1 += x1.x * a.x + x1.y * a.y + x1.z * a.z + x1.w * a.w;
            acc2 += x2.x * a.x + x2.y * a.y + x2.z * a.z + x2.w * a.w;
            acc3 += x3.x * a.x + x3.y * a.y + x3.z * a.z + x3.w * a.w;
        }
        __syncthreads();
    }

    // T[b][s][n0 + mg*4 .. +3]  (contiguous float4, aligned)
    const float4 o = make_float4(acc0, acc1, acc2, acc3);
    *(float4*)&T[((long)(b * DST + s)) * NSEQ + n0 + mg * 4] = o;
}

// ---------------------------------------------------------------------------
// Kernel 2: in-place inclusive cumsum over n for each (b,s) row of T.
// 64 blocks (one per (b,s)), 256 threads, 32 contiguous elements per thread.
// ---------------------------------------------------------------------------
__global__ __launch_bounds__(256) void k2_scan(float* __restrict__ T) {
    __shared__ float sums[256];
    const int t = threadIdx.x;
    const int b = blockIdx.x >> 4;
    const int s = blockIdx.x & 15;
    float* row = T + ((long)(b * DST + s)) * NSEQ;
    const int base = t * 32;

    float v[32];
    #pragma unroll
    for (int j = 0; j < 8; ++j) {
        const float4 f = *(const float4*)&row[base + 4 * j];
        v[4 * j + 0] = f.x; v[4 * j + 1] = f.y;
        v[4 * j + 2] = f.z; v[4 * j + 3] = f.w;
    }
    float run = 0.f;
    #pragma unroll
    for (int i = 0; i < 32; ++i) { run += v[i]; v[i] = run; }

    sums[t] = run;
    const float total = run;
    __syncthreads();
    for (int off = 1; off < 256; off <<= 1) {
        const float u = (t >= off) ? sums[t - off] : 0.f;
        __syncthreads();
        sums[t] += u;
        __syncthreads();
    }
    const float excl = sums[t] - total;

    #pragma unroll
    for (int j = 0; j < 8; ++j) {
        const float4 f = make_float4(v[4 * j + 0] + excl, v[4 * j + 1] + excl,
                                     v[4 * j + 2] + excl, v[4 * j + 3] + excl);
        *(float4*)&row[base + 4 * j] = f;
    }
}

// ---------------------------------------------------------------------------
// Kernel 3: out[b][n][c] = sum_s T[b][s][n] * D[s][c]
// Block = 256 threads, 64 rows (n) per block; thread owns c-quad 4t..4t+3
// with D[s][quad] in 64 VGPRs; state tile staged (transposed) in LDS.
// ---------------------------------------------------------------------------
#define K3_W 64

__global__ __launch_bounds__(256) void k3_out(const float* __restrict__ T,
                                              const float* __restrict__ D,
                                              float* __restrict__ out) {
    __shared__ float sp[K3_W * 20];   // [n][s] padded 16->20 (16B-aligned rows)
    const int t  = threadIdx.x;
    const int b  = blockIdx.x >> 7;
    const int n0 = (blockIdx.x & 127) * K3_W;

    // stage state tile: sp[nn][s] = T[b][s][n0+nn]  (coalesced over n)
    #pragma unroll
    for (int j = 0; j < 4; ++j) {
        const int idx = j * 256 + t;
        const int ss  = idx >> 6;     // 0..15
        const int nn  = idx & 63;
        sp[nn * 20 + ss] = T[((long)(b * DST + ss)) * NSEQ + n0 + nn];
    }

    float4 dreg[16];
    #pragma unroll
    for (int ss = 0; ss < 16; ++ss)
        dreg[ss] = *(const float4*)&D[ss * DIM + 4 * t];

    __syncthreads();

    float* ob = out + ((long)(b * NSEQ + n0)) * DIM + 4 * t;
    for (int r = 0; r < K3_W; ++r) {
        const float4 s0 = *(const float4*)&sp[r * 20 + 0];
        const float4 s1 = *(const float4*)&sp[r * 20 + 4];
        const float4 s2 = *(const float4*)&sp[r * 20 + 8];
        const float4 s3 = *(const float4*)&sp[r * 20 + 12];
        const float sv[16] = {s0.x, s0.y, s0.z, s0.w, s1.x, s1.y, s1.z, s1.w,
                              s2.x, s2.y, s2.z, s2.w, s3.x, s3.y, s3.z, s3.w};
        float4 o = make_float4(0.f, 0.f, 0.f, 0.f);
        #pragma unroll
        for (int ss = 0; ss < 16; ++ss) {
            o.x += sv[ss] * dreg[ss].x;
            o.y += sv[ss] * dreg[ss].y;
            o.z += sv[ss] * dreg[ss].z;
            o.w += sv[ss] * dreg[ss].w;
        }
        *(float4*)(ob + (long)r * DIM) = o;
    }
}

// ---------------------------------------------------------------------------
extern "C" void kernel_launch(void* const* d_in, const int* in_sizes, int n_in,
                              void* d_out, int out_size, void* d_ws, size_t ws_size,
                              hipStream_t stream) {
    const float* x = (const float*)d_in[0];   // [4, 8192, 1024]
    const float* A = (const float*)d_in[1];   // [1024, 16]
    const float* D = (const float*)d_in[2];   // [16, 1024]
    float* out = (float*)d_out;               // [4, 8192, 1024]
    float* T   = (float*)d_ws;                // [4, 16, 8192] = 2 MiB scratch

    k1_gemm<<<dim3(NB * 128), dim3(256), 0, stream>>>(x, A, T);
    k2_scan<<<dim3(NB * DST), dim3(256), 0, stream>>>(T);
    k3_out <<<dim3(NB * 128), dim3(256), 0, stream>>>(T, D, out);
}